// Round 11
// baseline (501.275 us; speedup 1.0000x reference)
//
#include <hip/hip_runtime.h>
#include <hip/hip_bf16.h>

#define N_SRC_ 50000
#define N_DST_ 50000
#define INF_   128
#define OUTF_  128
#define NT_    3
#define FAN_   10
#define BM_    64

#define LOG2E_  1.4426950408889634f
#define LOG2E2_ 2.8853900817779268f

typedef __attribute__((ext_vector_type(8))) short          bf16x8;
typedef __attribute__((ext_vector_type(4))) float          f32x4;
typedef __attribute__((ext_vector_type(2))) float          f32x2;

__device__ __forceinline__ unsigned short f2bf(float f) {
  unsigned u = __float_as_uint(f);
  u = u + 0x7FFFu + ((u >> 16) & 1u);   // RNE
  return (unsigned short)(u >> 16);
}
__device__ __forceinline__ float frcp(float x) { return __builtin_amdgcn_rcpf(x); }
__device__ __forceinline__ float fexp2(float x) { return __builtin_amdgcn_exp2f(x); }

// async global->LDS, 16B per lane, dest = wave-uniform base + lane*16 (linear)
__device__ __forceinline__ void gload16(const unsigned short* g, unsigned short* l) {
  __builtin_amdgcn_global_load_lds(
      (const __attribute__((address_space(1))) void*)g,
      (__attribute__((address_space(3))) void*)l, 16, 0, 0);
}

// T19 schedule template for one LSTM step body (k=1..9):
//   2 idx ds_reads, 2 global_load_lds early; 8 b-frag reads ahead;
//   then 32x {4 MFMA (one b-frag's ct-quad) : 9 VALU (gates) : 1 DS_READ};
//   h-writes sink to the end. Masks: VALU=0x2 MFMA=0x8 VMEM_READ=0x20
//   DS_READ=0x100 DS_WRITE=0x200.
__device__ __forceinline__ void sgb_step() {
  __builtin_amdgcn_sched_group_barrier(0x100, 2, 0);
  __builtin_amdgcn_sched_group_barrier(0x020, 2, 0);
  __builtin_amdgcn_sched_group_barrier(0x100, 8, 0);
#pragma unroll
  for (int i = 0; i < 24; ++i) {
    __builtin_amdgcn_sched_group_barrier(0x008, 4, 0);
    __builtin_amdgcn_sched_group_barrier(0x002, 9, 0);
    __builtin_amdgcn_sched_group_barrier(0x100, 1, 0);
  }
#pragma unroll
  for (int i = 0; i < 8; ++i) {
    __builtin_amdgcn_sched_group_barrier(0x008, 4, 0);
    __builtin_amdgcn_sched_group_barrier(0x002, 9, 0);
  }
  __builtin_amdgcn_sched_group_barrier(0x200, 4, 0);
}

// ---------------- prep: feature fp32 -> bf16 ----------------
__global__ void prep_feat(const float* __restrict__ f, unsigned short* __restrict__ o, int n4) {
  int i = blockIdx.x * blockDim.x + threadIdx.x;
  if (i < n4) {
    float4 v = ((const float4*)f)[i];
    ushort4 r;
    r.x = f2bf(v.x); r.y = f2bf(v.y); r.z = f2bf(v.z); r.w = f2bf(v.w);
    ((ushort4*)o)[i] = r;
  }
}

// ---------------- prep: weight reorder + concat + bf16 ----------------
// LSTM weights/biases pre-scaled by log2e (gates i,f,o) or 2*log2e (gate g)
// so device gate math uses raw v_exp_f32 (exp2) with no input muls.
__global__ void prep_w(const float* __restrict__ W_ih, const float* __restrict__ W_hh,
                       const float* __restrict__ b_ih, const float* __restrict__ b_hh,
                       const float* __restrict__ fcs,  const float* __restrict__ fcn,
                       unsigned short* __restrict__ Wcat, unsigned short* __restrict__ W2cat,
                       float* __restrict__ bcat) {
  int i = blockIdx.x * blockDim.x + threadIdx.x;
  if (i < NT_ * 512 * 256) {
    int t = i / (512 * 256); int rem = i % (512 * 256);
    int nr = rem >> 8; int kk = rem & 255;
    int w = nr >> 6, ct = (nr >> 4) & 3, j = nr & 15;
    int col = ct * 128 + w * 16 + j;
    float v = (kk < 128) ? W_ih[(t * 512 + col) * 128 + kk]
                         : W_hh[(t * 512 + col) * 128 + (kk - 128)];
    v *= (ct == 2) ? LOG2E2_ : LOG2E_;
    Wcat[i] = f2bf(v);
  } else {
    int i2 = i - NT_ * 512 * 256;
    if (i2 < NT_ * 128 * 256) {
      int t = i2 / (128 * 256); int rem = i2 % (128 * 256);
      int n = rem >> 8; int kk = rem & 255;
      float v = (kk < 128) ? fcs[(t * 128 + n) * 128 + kk]
                           : fcn[(t * 128 + n) * 128 + (kk - 128)];
      W2cat[i2] = f2bf(v);
    } else {
      int i3 = i2 - NT_ * 128 * 256;
      if (i3 < NT_ * 512) {
        int t = i3 / 512; int nr = i3 % 512;
        int ct = (nr >> 4) & 3;
        int col = ct * 128 + (nr >> 6) * 16 + (nr & 15);
        float s = (ct == 2) ? LOG2E2_ : LOG2E_;
        bcat[i3] = (b_ih[t * 512 + col] + b_hh[t * 512 + col]) * s;
      }
    }
  }
}

// ---------------- main fused kernel ----------------
// Operand-swapped MFMAs (R7): gates^T = W·x^T; lane owns (dst-row lr, 4 units).
// R8: gate diet v2. R9: 4-deep rt pipeline. R10: peel k=0 (branch-free main
// body), T19 sched_group_barrier template, bias-as-C (kk=0 MFMA C=biasv).
__global__ __launch_bounds__(512, 2) void sage_main(
    const unsigned short* __restrict__ feat16, const int* __restrict__ nidx,
    const unsigned short* __restrict__ Wcat, const float* __restrict__ bcat,
    const unsigned short* __restrict__ W2cat,
    const float* __restrict__ sbias, const float* __restrict__ lnw,
    const float* __restrict__ lnb, float* __restrict__ out) {
  const int t  = blockIdx.y;
  const int r0 = blockIdx.x * BM_;
  const int tid = threadIdx.x;
  const int w  = tid >> 6;     // wave 0..7: owns hidden units [16w,16w+16)
  const int l  = tid & 63;
  const int lg = l >> 4;       // k-group / unit sub-group
  const int lr = l & 15;       // dst-row within tile

  __shared__ __align__(16) unsigned short lds_x[2][BM_ * INF_];
  __shared__ __align__(16) unsigned short lds_h[2][BM_ * INF_];
  __shared__ int   lds_idx[BM_ * FAN_ + 32];   // +32 pad: dead ternary read at k=9
  __shared__ float lds_ps[BM_ * 8];
  __shared__ float lds_pq[BM_ * 8];
  __shared__ float lds_mu[BM_];
  __shared__ float lds_ri[BM_];

  // neighbor indices: clamp + pre-scale to row offset (shorts) once
  for (int i = tid; i < BM_ * FAN_; i += 512) {
    int row = i / FAN_;
    int v = 0;
    if (r0 + row < N_DST_) v = nidx[(t * N_DST_ + r0) * FAN_ + i];
    v = min(max(v, 0), N_SRC_ - 1);
    lds_idx[i] = v * INF_;
  }

  // register-resident LSTM weights: wave w's 64 rows of Wcat (A-operand)
  bf16x8 wfrag[4][8];
  {
    const unsigned short* wb = Wcat + (t * 512 + w * 64) * 256;
#pragma unroll
    for (int ct = 0; ct < 4; ++ct)
#pragma unroll
      for (int kk = 0; kk < 8; ++kk)
        wfrag[ct][kk] = *(const bf16x8*)(wb + (ct * 16 + lr) * 256 + kk * 32 + lg * 8);
  }
  // bias per (ct, unit=lg*4+j) as f32x4 vectors (acc layout after swap)
  f32x4 biasv[4];
#pragma unroll
  for (int ct = 0; ct < 4; ++ct)
#pragma unroll
    for (int j = 0; j < 4; ++j)
      biasv[ct][j] = bcat[t * 512 + w * 64 + ct * 16 + lg * 4 + j];

  float cst[16];   // c-state: (row-tile rt, unit j)
#pragma unroll
  for (int q = 0; q < 16; ++q) cst[q] = 0.f;

  const int grow = tid >> 4;                 // gather rows: grow, grow+32
  const int gch  = tid & 15;
  const int gsw  = (gch ^ (grow & 7)) * 8;   // pre-swizzled source chunk (shorts)
  const int wb0  = (w * 4) * INF_;           // wave-uniform LDS dest bases
  const int wb1  = (w * 4 + 32) * INF_;
  const int amask = (lr & 7) << 3;           // B-read swizzle mask (shorts)
  const int hcw   = w * 2 + (lg >> 1);       // h-write chunk index
  const int hoff  = (lg & 1) << 2;           // within-chunk short offset
  const int self0 = min(r0 + grow, N_DST_ - 1) * INF_;
  const int self1 = min(r0 + grow + 32, N_DST_ - 1) * INF_;

  __syncthreads();                           // lds_idx visible

  // prologue: gather step 0 into x[0]
  {
    int o0 = lds_idx[grow * FAN_];
    int o1 = lds_idx[(grow + 32) * FAN_];
    gload16(feat16 + o0 + gsw, &lds_x[0][wb0]);
    gload16(feat16 + o1 + gsw, &lds_x[0][wb1]);
  }
  __syncthreads();                           // drains vmcnt -> x[0] ready

  // gates for one rt sub-tile (shared by peel + main loop via hw param)
  auto gates_rt = [&](f32x4* acc, int rt, unsigned short* hw) {
    float hv[4];
#pragma unroll
    for (int jp = 0; jp < 2; ++jp) {
      f32x2 gi = {acc[0][jp * 2], acc[0][jp * 2 + 1]};
      f32x2 gf = {acc[1][jp * 2], acc[1][jp * 2 + 1]};
      f32x2 gg = {acc[2][jp * 2], acc[2][jp * 2 + 1]};
      f32x2 go = {acc[3][jp * 2], acc[3][jp * 2 + 1]};
      f32x2 ei, ef, Eg, eo;
      ei[0] = fexp2(-gi[0]); ei[1] = fexp2(-gi[1]);
      ef[0] = fexp2(-gf[0]); ef[1] = fexp2(-gf[1]);
      Eg[0] = fexp2(gg[0]);  Eg[1] = fexp2(gg[1]);
      eo[0] = fexp2(-go[0]); eo[1] = fexp2(-go[1]);
      f32x2 A = ef + 1.f;
      f32x2 B = ei + 1.f;
      f32x2 E = Eg + 1.f;
      f32x2 F = Eg - 1.f;
      f32x2 cp = {cst[rt * 4 + jp * 2], cst[rt * 4 + jp * 2 + 1]};
      f32x2 BE = B * E;
      f32x2 den = A * BE;
      f32x2 r; r[0] = frcp(den[0]); r[1] = frcp(den[1]);
      f32x2 c2 = (cp * BE + F * A) * r;
      cst[rt * 4 + jp * 2]     = c2[0];
      cst[rt * 4 + jp * 2 + 1] = c2[1];
      f32x2 xc = c2 * LOG2E2_;
      f32x2 Ec; Ec[0] = fexp2(xc[0]); Ec[1] = fexp2(xc[1]);
      f32x2 G = Ec - 1.f;
      f32x2 H = (eo + 1.f) * (Ec + 1.f);
      f32x2 rr; rr[0] = frcp(H[0]); rr[1] = frcp(H[1]);
      f32x2 hvv = G * rr;
      hv[jp * 2] = hvv[0]; hv[jp * 2 + 1] = hvv[1];
    }
    unsigned p01, p23;
    asm("v_cvt_pk_bf16_f32 %0, %1, %2" : "=v"(p01) : "v"(hv[0]), "v"(hv[1]));
    asm("v_cvt_pk_bf16_f32 %0, %1, %2" : "=v"(p23) : "v"(hv[2]), "v"(hv[3]));
    const int row = rt * 16 + lr;
    const int saddr = row * INF_ + (((hcw ^ (row & 7)) << 3) + hoff);
    uint2 pk; pk.x = p01; pk.y = p23;
    *(uint2*)(hw + saddr) = pk;          // one ds_write_b64
  };

  // ---- step k = 0 (peeled: h == 0, x-half MFMAs only; bias as MFMA C) ----
  {
    const unsigned short* xb = lds_x[0];
    unsigned short* hw = lds_h[1];
    // prefetch step-1 gather into x[1]
    {
      int o0 = lds_idx[grow * FAN_ + 1];
      int o1 = lds_idx[(grow + 32) * FAN_ + 1];
      gload16(feat16 + o0 + gsw, &lds_x[1][wb0]);
      gload16(feat16 + o1 + gsw, &lds_x[1][wb1]);
    }
    auto mfma_x = [&](f32x4* acc, int rt) {
      const int rowb = (rt * 16 + lr) * INF_;
      bf16x8 b0 = *(const bf16x8*)(xb + rowb + ((lg * 8) ^ amask));
#pragma unroll
      for (int ct = 0; ct < 4; ++ct)
        acc[ct] = __builtin_amdgcn_mfma_f32_16x16x32_bf16(wfrag[ct][0], b0, biasv[ct], 0, 0, 0);
#pragma unroll
      for (int kk = 1; kk < 4; ++kk) {
        bf16x8 b = *(const bf16x8*)(xb + rowb + ((kk * 32 + lg * 8) ^ amask));
#pragma unroll
        for (int ct = 0; ct < 4; ++ct)
          acc[ct] = __builtin_amdgcn_mfma_f32_16x16x32_bf16(wfrag[ct][kk], b, acc[ct], 0, 0, 0);
      }
    };
    f32x4 accA[4], accB[4];
    mfma_x(accA, 0);
    mfma_x(accB, 1);
    gates_rt(accA, 0, hw);
    mfma_x(accA, 2);
    gates_rt(accB, 1, hw);
    mfma_x(accB, 3);
    gates_rt(accA, 2, hw);
    gates_rt(accB, 3, hw);
    __syncthreads();
  }

  // ---- steps k = 1..9: branch-free body + T19 schedule template ----
#pragma unroll 1
  for (int k = 1; k < FAN_; ++k) {
    const int cb = k & 1, nb = cb ^ 1;

    // branchless prefetch: gather k+1, or self-features on the last step.
    // (lds_idx padded; the dead read at k=9 is discarded by the select)
    {
      int o0 = lds_idx[grow * FAN_ + k + 1];
      int o1 = lds_idx[(grow + 32) * FAN_ + k + 1];
      o0 = (k < FAN_ - 1) ? o0 : self0;
      o1 = (k < FAN_ - 1) ? o1 : self1;
      gload16(feat16 + o0 + gsw, &lds_x[nb][wb0]);
      gload16(feat16 + o1 + gsw, &lds_x[nb][wb1]);
    }

    const unsigned short* xb = lds_x[cb];
    const unsigned short* hb = lds_h[cb];
    unsigned short* hw = lds_h[nb];

    auto mfma_xh = [&](f32x4* acc, int rt) {
      const int rowb = (rt * 16 + lr) * INF_;
      bf16x8 b0 = *(const bf16x8*)(xb + rowb + ((lg * 8) ^ amask));
#pragma unroll
      for (int ct = 0; ct < 4; ++ct)
        acc[ct] = __builtin_amdgcn_mfma_f32_16x16x32_bf16(wfrag[ct][0], b0, biasv[ct], 0, 0, 0);
#pragma unroll
      for (int kk = 1; kk < 8; ++kk) {
        bf16x8 b = (kk < 4)
            ? *(const bf16x8*)(xb + rowb + ((kk * 32 + lg * 8) ^ amask))
            : *(const bf16x8*)(hb + rowb + (((kk - 4) * 32 + lg * 8) ^ amask));
#pragma unroll
        for (int ct = 0; ct < 4; ++ct)
          acc[ct] = __builtin_amdgcn_mfma_f32_16x16x32_bf16(wfrag[ct][kk], b, acc[ct], 0, 0, 0);
      }
    };

    // 4-deep pipeline source order; SGB template enforces the interleave
    f32x4 accA[4], accB[4];
    mfma_xh(accA, 0);
    mfma_xh(accB, 1);
    gates_rt(accA, 0, hw);
    mfma_xh(accA, 2);
    gates_rt(accB, 1, hw);
    mfma_xh(accB, 3);
    gates_rt(accA, 2, hw);
    gates_rt(accB, 3, hw);

    sgb_step();

    // single barrier/step: drains vmcnt (prefetch) + lgkmcnt (h writes)
    __syncthreads();
  }

  // ---------- epilogue ----------
  // k=9 wrote self-features into x[0] and final h into h[0]
  bf16x8 w2f[8];
  {
    const unsigned short* w2b = W2cat + (t * 128 + w * 16) * 256;
#pragma unroll
    for (int kk = 0; kk < 8; ++kk)
      w2f[kk] = *(const bf16x8*)(w2b + lr * 256 + kk * 32 + lg * 8);
  }
  f32x4 b2v, lwv, lbv;
#pragma unroll
  for (int j = 0; j < 4; ++j) {
    b2v[j] = sbias[t * 128 + w * 16 + lg * 4 + j];
    lwv[j] = lnw[t * 128 + w * 16 + lg * 4 + j];
    lbv[j] = lnb[t * 128 + w * 16 + lg * 4 + j];
  }

  f32x4 a2[4];
  {
    const unsigned short* xb = lds_x[0];
    const unsigned short* hb = lds_h[0];
    __builtin_amdgcn_s_setprio(1);
#pragma unroll
    for (int rt = 0; rt < 4; ++rt) {
      const int rowb = (rt * 16 + lr) * INF_;
      bf16x8 b0 = *(const bf16x8*)(xb + rowb + ((lg * 8) ^ amask));
      a2[rt] = __builtin_amdgcn_mfma_f32_16x16x32_bf16(w2f[0], b0, b2v, 0, 0, 0);
    }
#pragma unroll
    for (int kk = 1; kk < 8; ++kk) {
#pragma unroll
      for (int rt = 0; rt < 4; ++rt) {
        const int rowb = (rt * 16 + lr) * INF_;
        bf16x8 b = (kk < 4)
            ? *(const bf16x8*)(xb + rowb + ((kk * 32 + lg * 8) ^ amask))
            : *(const bf16x8*)(hb + rowb + (((kk - 4) * 32 + lg * 8) ^ amask));
        a2[rt] = __builtin_amdgcn_mfma_f32_16x16x32_bf16(w2f[kk], b, a2[rt], 0, 0, 0);
      }
    }
    __builtin_amdgcn_s_setprio(0);
  }

  // LayerNorm: lane has 4 cols of row rt*16+lr; j-sum in-register, then
  // 2-step butterfly over lg (xor 16, 32), then 8-wave LDS combine.
#pragma unroll
  for (int rt = 0; rt < 4; ++rt) {
    float s = a2[rt][0] + a2[rt][1] + a2[rt][2] + a2[rt][3];
    float q = a2[rt][0] * a2[rt][0] + a2[rt][1] * a2[rt][1]
            + a2[rt][2] * a2[rt][2] + a2[rt][3] * a2[rt][3];
    s += __shfl_xor(s, 16, 64); q += __shfl_xor(q, 16, 64);
    s += __shfl_xor(s, 32, 64); q += __shfl_xor(q, 32, 64);
    if (lg == 0) {
      int row = rt * 16 + lr;
      lds_ps[row * 8 + w] = s;
      lds_pq[row * 8 + w] = q;
    }
  }
  __syncthreads();
  if (tid < BM_) {
    float s = 0.f, q = 0.f;
#pragma unroll
    for (int wv = 0; wv < 8; ++wv) { s += lds_ps[tid * 8 + wv]; q += lds_pq[tid * 8 + wv]; }
    float mu = s * (1.f / 128.f);
    float var = q * (1.f / 128.f) - mu * mu;
    lds_mu[tid] = mu;
    lds_ri[tid] = rsqrtf(var + 1e-12f);
  }
  __syncthreads();
#pragma unroll
  for (int rt = 0; rt < 4; ++rt) {
    int row = rt * 16 + lr;
    if (r0 + row < N_DST_) {
      float mu = lds_mu[row], ri = lds_ri[row];
      float4 o;
      float y0 = (a2[rt][0] - mu) * ri * lwv[0] + lbv[0];
      float y1 = (a2[rt][1] - mu) * ri * lwv[1] + lbv[1];
      float y2 = (a2[rt][2] - mu) * ri * lwv[2] + lbv[2];
      float y3 = (a2[rt][3] - mu) * ri * lwv[3] + lbv[3];
      o.x = (y0 > 0.f) ? y0 : (fexp2(y0 * LOG2E_) - 1.f);
      o.y = (y1 > 0.f) ? y1 : (fexp2(y1 * LOG2E_) - 1.f);
      o.z = (y2 > 0.f) ? y2 : (fexp2(y2 * LOG2E_) - 1.f);
      o.w = (y3 > 0.f) ? y3 : (fexp2(y3 * LOG2E_) - 1.f);
      *(float4*)(out + (size_t)(r0 + row) * (NT_ * OUTF_) + t * OUTF_ + w * 16 + lg * 4) = o;
    }
  }
}

extern "C" void kernel_launch(void* const* d_in, const int* in_sizes, int n_in,
                              void* d_out, int out_size, void* d_ws, size_t ws_size,
                              hipStream_t stream) {
  (void)in_sizes; (void)n_in; (void)out_size; (void)ws_size;
  const float* feature = (const float*)d_in[0];
  const int*   nidx    = (const int*)d_in[1];
  const float* W_ih    = (const float*)d_in[2];
  const float* W_hh    = (const float*)d_in[3];
  const float* b_ih    = (const float*)d_in[4];
  const float* b_hh    = (const float*)d_in[5];
  const float* fcs     = (const float*)d_in[6];
  const float* fcn     = (const float*)d_in[7];
  const float* sbias   = (const float*)d_in[8];
  const float* lnw     = (const float*)d_in[9];
  const float* lnb     = (const float*)d_in[10];
  float* out = (float*)d_out;

  char* ws = (char*)d_ws;
  unsigned short* feat16 = (unsigned short*)ws;                              // 12,800,000 B
  unsigned short* Wcat   = (unsigned short*)(ws + 12800000);                 //    786,432 B
  unsigned short* W2cat  = (unsigned short*)(ws + 12800000 + 786432);        //    196,608 B
  float*          bcat   = (float*)(ws + 12800000 + 786432 + 196608);        //      6,144 B

  int n4 = N_SRC_ * INF_ / 4;
  prep_feat<<<(n4 + 255) / 256, 256, 0, stream>>>(feature, feat16, n4);
  int ptot = NT_ * 512 * 256 + NT_ * 128 * 256 + NT_ * 512;
  prep_w<<<(ptot + 255) / 256, 256, 0, stream>>>(W_ih, W_hh, b_ih, b_hh, fcs, fcn, Wcat, W2cat, bcat);

  dim3 grid((N_DST_ + BM_ - 1) / BM_, NT_);
  sage_main<<<grid, 512, 0, stream>>>(feat16, nidx, Wcat, bcat, W2cat, sbias, lnw, lnb, out);
}

// Round 13
// 493.657 us; speedup vs baseline: 1.0154x; 1.0154x over previous
//
#include <hip/hip_runtime.h>
#include <hip/hip_bf16.h>

#define N_SRC_ 50000
#define N_DST_ 50000
#define INF_   128
#define OUTF_  128
#define NT_    3
#define FAN_   10
#define BM_    64

#define LOG2E_  1.4426950408889634f
#define LOG2E2_ 2.8853900817779268f

typedef __attribute__((ext_vector_type(8))) short          bf16x8;
typedef __attribute__((ext_vector_type(4))) float          f32x4;
typedef __attribute__((ext_vector_type(2))) float          f32x2;

__device__ __forceinline__ unsigned short f2bf(float f) {
  unsigned u = __float_as_uint(f);
  u = u + 0x7FFFu + ((u >> 16) & 1u);   // RNE
  return (unsigned short)(u >> 16);
}
__device__ __forceinline__ float frcp(float x) { return __builtin_amdgcn_rcpf(x); }
__device__ __forceinline__ float fexp2(float x) { return __builtin_amdgcn_exp2f(x); }

// async global->LDS, 16B per lane, dest = wave-uniform base + lane*16 (linear)
__device__ __forceinline__ void gload16(const unsigned short* g, unsigned short* l) {
  __builtin_amdgcn_global_load_lds(
      (const __attribute__((address_space(1))) void*)g,
      (__attribute__((address_space(3))) void*)l, 16, 0, 0);
}

// ---------------- merged prep: feat->bf16 + weight reorder/concat ----------------
// [0, n4): feature fp32 -> bf16 (float4/ushort4 vectorized)
// [n4, n4+NT*512*256): Wcat (LSTM weights, gate-reordered, exp2-prescaled)
// then W2cat (fc_self|fc_neigh concat), then bcat (b_ih+b_hh, prescaled).
__global__ void prep_all(const float* __restrict__ feature,
                         const float* __restrict__ W_ih, const float* __restrict__ W_hh,
                         const float* __restrict__ b_ih, const float* __restrict__ b_hh,
                         const float* __restrict__ fcs,  const float* __restrict__ fcn,
                         unsigned short* __restrict__ feat16,
                         unsigned short* __restrict__ Wcat,
                         unsigned short* __restrict__ W2cat,
                         float* __restrict__ bcat, int n4) {
  int gi = blockIdx.x * blockDim.x + threadIdx.x;
  if (gi < n4) {
    float4 v = ((const float4*)feature)[gi];
    ushort4 r;
    r.x = f2bf(v.x); r.y = f2bf(v.y); r.z = f2bf(v.z); r.w = f2bf(v.w);
    ((ushort4*)feat16)[gi] = r;
    return;
  }
  int i = gi - n4;
  if (i < NT_ * 512 * 256) {
    int t = i / (512 * 256); int rem = i % (512 * 256);
    int nr = rem >> 8; int kk = rem & 255;
    int w = nr >> 6, ct = (nr >> 4) & 3, j = nr & 15;
    int col = ct * 128 + w * 16 + j;
    float v = (kk < 128) ? W_ih[(t * 512 + col) * 128 + kk]
                         : W_hh[(t * 512 + col) * 128 + (kk - 128)];
    v *= (ct == 2) ? LOG2E2_ : LOG2E_;
    Wcat[i] = f2bf(v);
  } else {
    int i2 = i - NT_ * 512 * 256;
    if (i2 < NT_ * 128 * 256) {
      int t = i2 / (128 * 256); int rem = i2 % (128 * 256);
      int n = rem >> 8; int kk = rem & 255;
      float v = (kk < 128) ? fcs[(t * 128 + n) * 128 + kk]
                           : fcn[(t * 128 + n) * 128 + (kk - 128)];
      W2cat[i2] = f2bf(v);
    } else {
      int i3 = i2 - NT_ * 128 * 256;
      if (i3 < NT_ * 512) {
        int t = i3 / 512; int nr = i3 % 512;
        int ct = (nr >> 4) & 3;
        int col = ct * 128 + (nr >> 6) * 16 + (nr & 15);
        float s = (ct == 2) ? LOG2E2_ : LOG2E_;
        bcat[i3] = (b_ih[t * 512 + col] + b_hh[t * 512 + col]) * s;
      }
    }
  }
}

// ---------------- main fused kernel (R9 known-good, banked) ----------------
// Operand-swapped MFMAs (R7): gates^T = W·x^T; lane owns (dst-row lr, 4 units).
// R8: gate diet v2 (exp2-prescaled weights, single-rcp c-update, f32x2 packed).
// R9: 4-deep rt pipeline: M(rt0)A M(rt1)B g(rt0) M(rt2)A g(rt1) M(rt3)B g(rt2)
// g(rt3); peak live acc = 2 tiles (32 regs). Spill tripwire: WRITE > 90 MB.
// (R11's K-split partial pipeline failed NaN, bug unlocalized — reverted.)
__global__ __launch_bounds__(512, 2) void sage_main(
    const unsigned short* __restrict__ feat16, const int* __restrict__ nidx,
    const unsigned short* __restrict__ Wcat, const float* __restrict__ bcat,
    const unsigned short* __restrict__ W2cat,
    const float* __restrict__ sbias, const float* __restrict__ lnw,
    const float* __restrict__ lnb, float* __restrict__ out) {
  const int t  = blockIdx.y;
  const int r0 = blockIdx.x * BM_;
  const int tid = threadIdx.x;
  const int w  = tid >> 6;     // wave 0..7: owns hidden units [16w,16w+16)
  const int l  = tid & 63;
  const int lg = l >> 4;       // unit sub-group
  const int lr = l & 15;       // dst-row within tile

  __shared__ __align__(16) unsigned short lds_x[2][BM_ * INF_];
  __shared__ __align__(16) unsigned short lds_h[2][BM_ * INF_];
  __shared__ int   lds_idx[BM_ * FAN_];
  __shared__ float lds_ps[BM_ * 8];
  __shared__ float lds_pq[BM_ * 8];
  __shared__ float lds_mu[BM_];
  __shared__ float lds_ri[BM_];

  // neighbor indices: clamp + pre-scale to row offset (shorts) once
  for (int i = tid; i < BM_ * FAN_; i += 512) {
    int row = i / FAN_;
    int v = 0;
    if (r0 + row < N_DST_) v = nidx[(t * N_DST_ + r0) * FAN_ + i];
    v = min(max(v, 0), N_SRC_ - 1);
    lds_idx[i] = v * INF_;
  }

  // register-resident LSTM weights: wave w's 64 rows of Wcat (A-operand)
  bf16x8 wfrag[4][8];
  {
    const unsigned short* wb = Wcat + (t * 512 + w * 64) * 256;
#pragma unroll
    for (int ct = 0; ct < 4; ++ct)
#pragma unroll
      for (int kk = 0; kk < 8; ++kk)
        wfrag[ct][kk] = *(const bf16x8*)(wb + (ct * 16 + lr) * 256 + kk * 32 + lg * 8);
  }
  // bias per (ct, unit=lg*4+j) as f32x4 vectors (acc layout after swap)
  f32x4 biasv[4];
#pragma unroll
  for (int ct = 0; ct < 4; ++ct)
#pragma unroll
    for (int j = 0; j < 4; ++j)
      biasv[ct][j] = bcat[t * 512 + w * 64 + ct * 16 + lg * 4 + j];

  float cst[16];
#pragma unroll
  for (int q = 0; q < 16; ++q) cst[q] = 0.f;

  const int grow = tid >> 4;                 // gather rows: grow, grow+32
  const int gch  = tid & 15;
  const int gsw  = (gch ^ (grow & 7)) * 8;   // pre-swizzled source chunk (shorts)
  const int wb0  = (w * 4) * INF_;           // wave-uniform LDS dest bases
  const int wb1  = (w * 4 + 32) * INF_;
  const int amask = (lr & 7) << 3;           // B-read swizzle mask (shorts)
  const int hcw   = w * 2 + (lg >> 1);       // h-write chunk index
  const int hoff  = (lg & 1) << 2;           // within-chunk short offset

  __syncthreads();                           // lds_idx visible

  // prologue: gather step 0 into x[0]
  {
    int o0 = lds_idx[grow * FAN_];
    int o1 = lds_idx[(grow + 32) * FAN_];
    gload16(feat16 + o0 + gsw, &lds_x[0][wb0]);
    gload16(feat16 + o1 + gsw, &lds_x[0][wb1]);
  }
  __syncthreads();                           // drains vmcnt -> x[0] ready

#pragma unroll 1
  for (int k = 0; k < FAN_; ++k) {
    const int cb = k & 1, nb = cb ^ 1;

    // prefetch next tile (step k+1 gather, or self-features for epilogue)
    if (k + 1 < FAN_) {
      int o0 = lds_idx[grow * FAN_ + k + 1];
      int o1 = lds_idx[(grow + 32) * FAN_ + k + 1];
      gload16(feat16 + o0 + gsw, &lds_x[nb][wb0]);
      gload16(feat16 + o1 + gsw, &lds_x[nb][wb1]);
    } else {
      int s0 = min(r0 + grow, N_DST_ - 1) * INF_;
      int s1 = min(r0 + grow + 32, N_DST_ - 1) * INF_;
      gload16(feat16 + s0 + gsw, &lds_x[nb][wb0]);
      gload16(feat16 + s1 + gsw, &lds_x[nb][wb1]);
    }

    const unsigned short* xb = lds_x[cb];
    const unsigned short* hb = lds_h[cb];
    unsigned short* hw = lds_h[nb];

    // MFMA cluster for one rt sub-tile (16 dst rows): 8 b128 reads + 32 MFMA
    auto mfma_rt = [&](f32x4* acc, int rt) {
#pragma unroll
      for (int ct = 0; ct < 4; ++ct) acc[ct] = biasv[ct];
      __builtin_amdgcn_s_setprio(1);
#pragma unroll
      for (int kk = 0; kk < 8; ++kk) {
        if (kk >= 4 && k == 0) continue;   // h==0 at step 0 (uniform branch)
        const int rowb = (rt * 16 + lr) * INF_;
        bf16x8 b = (kk < 4)
            ? *(const bf16x8*)(xb + rowb + ((kk * 32 + lg * 8) ^ amask))
            : *(const bf16x8*)(hb + rowb + (((kk - 4) * 32 + lg * 8) ^ amask));
#pragma unroll
        for (int ct = 0; ct < 4; ++ct)   // A=weights, B=rows (swapped)
          acc[ct] = __builtin_amdgcn_mfma_f32_16x16x32_bf16(wfrag[ct][kk], b, acc[ct], 0, 0, 0);
      }
      __builtin_amdgcn_s_setprio(0);
    };

    // gates for one rt sub-tile: f32x2 packed, 5 exp2 + 2 rcp per elem
    auto gates_rt = [&](f32x4* acc, int rt) {
      float hv[4];
#pragma unroll
      for (int jp = 0; jp < 2; ++jp) {
        f32x2 gi = {acc[0][jp * 2], acc[0][jp * 2 + 1]};
        f32x2 gf = {acc[1][jp * 2], acc[1][jp * 2 + 1]};
        f32x2 gg = {acc[2][jp * 2], acc[2][jp * 2 + 1]};
        f32x2 go = {acc[3][jp * 2], acc[3][jp * 2 + 1]};
        f32x2 ei, ef, Eg, eo;
        ei[0] = fexp2(-gi[0]); ei[1] = fexp2(-gi[1]);
        ef[0] = fexp2(-gf[0]); ef[1] = fexp2(-gf[1]);
        Eg[0] = fexp2(gg[0]);  Eg[1] = fexp2(gg[1]);
        eo[0] = fexp2(-go[0]); eo[1] = fexp2(-go[1]);
        f32x2 A = ef + 1.f;
        f32x2 B = ei + 1.f;
        f32x2 E = Eg + 1.f;
        f32x2 F = Eg - 1.f;
        f32x2 cp = {cst[rt * 4 + jp * 2], cst[rt * 4 + jp * 2 + 1]};
        f32x2 BE = B * E;
        f32x2 den = A * BE;
        f32x2 r; r[0] = frcp(den[0]); r[1] = frcp(den[1]);
        f32x2 c2 = (cp * BE + F * A) * r;
        cst[rt * 4 + jp * 2]     = c2[0];
        cst[rt * 4 + jp * 2 + 1] = c2[1];
        f32x2 xc = c2 * LOG2E2_;
        f32x2 Ec; Ec[0] = fexp2(xc[0]); Ec[1] = fexp2(xc[1]);
        f32x2 G = Ec - 1.f;
        f32x2 H = (eo + 1.f) * (Ec + 1.f);
        f32x2 rr; rr[0] = frcp(H[0]); rr[1] = frcp(H[1]);
        f32x2 hvv = G * rr;
        hv[jp * 2] = hvv[0]; hv[jp * 2 + 1] = hvv[1];
      }
      unsigned p01, p23;
      asm("v_cvt_pk_bf16_f32 %0, %1, %2" : "=v"(p01) : "v"(hv[0]), "v"(hv[1]));
      asm("v_cvt_pk_bf16_f32 %0, %1, %2" : "=v"(p23) : "v"(hv[2]), "v"(hv[3]));
      const int row = rt * 16 + lr;
      const int saddr = row * INF_ + (((hcw ^ (row & 7)) << 3) + hoff);
      uint2 pk; pk.x = p01; pk.y = p23;
      *(uint2*)(hw + saddr) = pk;          // one ds_write_b64
    };

    // 4-deep pipeline: gates(rt_i) overlap MFMAs(rt_{i+1}); <=2 acc tiles live
    f32x4 accA[4], accB[4];
    mfma_rt(accA, 0);
    mfma_rt(accB, 1);
    gates_rt(accA, 0);
    mfma_rt(accA, 2);
    gates_rt(accB, 1);
    mfma_rt(accB, 3);
    gates_rt(accA, 2);
    gates_rt(accB, 3);

    // single barrier/step: drains vmcnt (prefetch) + lgkmcnt (h writes)
    __syncthreads();
  }

  // ---------- epilogue ----------
  // k=9 wrote self-features into x[0] and final h into h[0]
  bf16x8 w2f[8];
  {
    const unsigned short* w2b = W2cat + (t * 128 + w * 16) * 256;
#pragma unroll
    for (int kk = 0; kk < 8; ++kk)
      w2f[kk] = *(const bf16x8*)(w2b + lr * 256 + kk * 32 + lg * 8);
  }
  f32x4 b2v, lwv, lbv;
#pragma unroll
  for (int j = 0; j < 4; ++j) {
    b2v[j] = sbias[t * 128 + w * 16 + lg * 4 + j];
    lwv[j] = lnw[t * 128 + w * 16 + lg * 4 + j];
    lbv[j] = lnb[t * 128 + w * 16 + lg * 4 + j];
  }

  f32x4 a2[4];
#pragma unroll
  for (int rt = 0; rt < 4; ++rt) a2[rt] = b2v;
  {
    const unsigned short* xb = lds_x[0];
    const unsigned short* hb = lds_h[0];
    __builtin_amdgcn_s_setprio(1);
#pragma unroll
    for (int kk = 0; kk < 8; ++kk) {
#pragma unroll
      for (int rt = 0; rt < 4; ++rt) {
        const int rowb = (rt * 16 + lr) * INF_;
        bf16x8 b = (kk < 4)
            ? *(const bf16x8*)(xb + rowb + ((kk * 32 + lg * 8) ^ amask))
            : *(const bf16x8*)(hb + rowb + (((kk - 4) * 32 + lg * 8) ^ amask));
        a2[rt] = __builtin_amdgcn_mfma_f32_16x16x32_bf16(w2f[kk], b, a2[rt], 0, 0, 0);
      }
    }
    __builtin_amdgcn_s_setprio(0);
  }

  // LayerNorm: lane has 4 cols of row rt*16+lr; j-sum in-register, then
  // 2-step butterfly over lg (xor 16, 32), then 8-wave LDS combine.
#pragma unroll
  for (int rt = 0; rt < 4; ++rt) {
    float s = a2[rt][0] + a2[rt][1] + a2[rt][2] + a2[rt][3];
    float q = a2[rt][0] * a2[rt][0] + a2[rt][1] * a2[rt][1]
            + a2[rt][2] * a2[rt][2] + a2[rt][3] * a2[rt][3];
    s += __shfl_xor(s, 16, 64); q += __shfl_xor(q, 16, 64);
    s += __shfl_xor(s, 32, 64); q += __shfl_xor(q, 32, 64);
    if (lg == 0) {
      int row = rt * 16 + lr;
      lds_ps[row * 8 + w] = s;
      lds_pq[row * 8 + w] = q;
    }
  }
  __syncthreads();
  if (tid < BM_) {
    float s = 0.f, q = 0.f;
#pragma unroll
    for (int wv = 0; wv < 8; ++wv) { s += lds_ps[tid * 8 + wv]; q += lds_pq[tid * 8 + wv]; }
    float mu = s * (1.f / 128.f);
    float var = q * (1.f / 128.f) - mu * mu;
    lds_mu[tid] = mu;
    lds_ri[tid] = rsqrtf(var + 1e-12f);
  }
  __syncthreads();
#pragma unroll
  for (int rt = 0; rt < 4; ++rt) {
    int row = rt * 16 + lr;
    if (r0 + row < N_DST_) {
      float mu = lds_mu[row], ri = lds_ri[row];
      float4 o;
      float y0 = (a2[rt][0] - mu) * ri * lwv[0] + lbv[0];
      float y1 = (a2[rt][1] - mu) * ri * lwv[1] + lbv[1];
      float y2 = (a2[rt][2] - mu) * ri * lwv[2] + lbv[2];
      float y3 = (a2[rt][3] - mu) * ri * lwv[3] + lbv[3];
      o.x = (y0 > 0.f) ? y0 : (fexp2(y0 * LOG2E_) - 1.f);
      o.y = (y1 > 0.f) ? y1 : (fexp2(y1 * LOG2E_) - 1.f);
      o.z = (y2 > 0.f) ? y2 : (fexp2(y2 * LOG2E_) - 1.f);
      o.w = (y3 > 0.f) ? y3 : (fexp2(y3 * LOG2E_) - 1.f);
      *(float4*)(out + (size_t)(r0 + row) * (NT_ * OUTF_) + t * OUTF_ + w * 16 + lg * 4) = o;
    }
  }
}

extern "C" void kernel_launch(void* const* d_in, const int* in_sizes, int n_in,
                              void* d_out, int out_size, void* d_ws, size_t ws_size,
                              hipStream_t stream) {
  (void)in_sizes; (void)n_in; (void)out_size; (void)ws_size;
  const float* feature = (const float*)d_in[0];
  const int*   nidx    = (const int*)d_in[1];
  const float* W_ih    = (const float*)d_in[2];
  const float* W_hh    = (const float*)d_in[3];
  const float* b_ih    = (const float*)d_in[4];
  const float* b_hh    = (const float*)d_in[5];
  const float* fcs     = (const float*)d_in[6];
  const float* fcn     = (const float*)d_in[7];
  const float* sbias   = (const float*)d_in[8];
  const float* lnw     = (const float*)d_in[9];
  const float* lnb     = (const float*)d_in[10];
  float* out = (float*)d_out;

  char* ws = (char*)d_ws;
  unsigned short* feat16 = (unsigned short*)ws;                              // 12,800,000 B
  unsigned short* Wcat   = (unsigned short*)(ws + 12800000);                 //    786,432 B
  unsigned short* W2cat  = (unsigned short*)(ws + 12800000 + 786432);        //    196,608 B
  float*          bcat   = (float*)(ws + 12800000 + 786432 + 196608);        //      6,144 B

  int n4 = N_SRC_ * INF_ / 4;
  int ptot = NT_ * 512 * 256 + NT_ * 128 * 256 + NT_ * 512;
  int tot = n4 + ptot;
  prep_all<<<(tot + 255) / 256, 256, 0, stream>>>(
      feature, W_ih, W_hh, b_ih, b_hh, fcs, fcn, feat16, Wcat, W2cat, bcat, n4);

  dim3 grid((N_DST_ + BM_ - 1) / BM_, NT_);
  sage_main<<<grid, 512, 0, stream>>>(feat16, nidx, Wcat, bcat, W2cat, sbias, lnw, lnb, out);
}